// Round 5
// baseline (55.770 us; speedup 1.0000x reference)
//
#include <hip/hip_runtime.h>
#include <hip/hip_bf16.h>

// Problem constants: B=16384, N=20, D=64, R=3, K=64
#define BB   16384
#define NN   20
#define NREL 3

typedef __attribute__((ext_vector_type(8))) short  short8;
typedef __attribute__((ext_vector_type(4))) float  f32x4;

__device__ __forceinline__ float lo16(unsigned int u) {
    union { unsigned int x; float f; } c; c.x = u << 16; return c.f;
}
__device__ __forceinline__ float hi16(unsigned int u) {
    union { unsigned int x; float f; } c; c.x = u & 0xFFFF0000u; return c.f;
}

// f32 -> bf16 (RNE), returned as raw ushort
__device__ __forceinline__ unsigned short f2bu(float f) {
    union { float f; unsigned int u; } x;
    x.f = f;
    unsigned int r = x.u + 0x7FFFu + ((x.u >> 16) & 1u);
    return (unsigned short)(r >> 16);
}

// ---------------------------------------------------------------------------
// K1: McatT[r*128+e][d] = sum_k w_uir[r][d][k] * w_aor[r][e][k]   (bf16 out)
//     cvec[r*128+e]     = sum_k r_vec[r][k]   * w_aor[r][e][k]    (f32 out)
// ---------------------------------------------------------------------------
__global__ __launch_bounds__(256) void k_precompute(
    const float* __restrict__ w_uir,
    const float* __restrict__ w_aor,
    const float* __restrict__ r_vec,
    unsigned short* __restrict__ McatT,   // [384][128] bf16 bits
    float* __restrict__ cvec)             // [384]
{
    int idx = blockIdx.x * 256 + threadIdx.x;
    if (idx < NREL * 128 * 128) {
        int d = idx & 127;
        int e = (idx >> 7) & 127;
        int r = idx >> 14;
        const float4* pu = reinterpret_cast<const float4*>(w_uir + (r * 128 + d) * 64);
        const float4* pa = reinterpret_cast<const float4*>(w_aor + (r * 128 + e) * 64);
        float acc = 0.f;
        #pragma unroll
        for (int k = 0; k < 16; ++k) {
            float4 a = pu[k], b = pa[k];
            acc += a.x * b.x + a.y * b.y + a.z * b.z + a.w * b.w;
        }
        McatT[(r * 128 + e) * 128 + d] = f2bu(acc);
    } else if (idx < NREL * 128 * 128 + NREL * 128) {
        int j = idx - NREL * 128 * 128;
        int r = j >> 7, e = j & 127;
        const float4* pr = reinterpret_cast<const float4*>(r_vec + r * 64);
        const float4* pa = reinterpret_cast<const float4*>(w_aor + (r * 128 + e) * 64);
        float acc = 0.f;
        #pragma unroll
        for (int k = 0; k < 16; ++k) {
            float4 a = pr[k], b = pa[k];
            acc += a.x * b.x + a.y * b.y + a.z * b.z + a.w * b.w;
        }
        cvec[j] = acc;
    }
}

// ---------------------------------------------------------------------------
// K2: v'[b][j] = sum_d ui_in[b][d] * McatT[j][d] + cvec[j]
//     GEMM M=16384 N=384 K=128, bf16 MFMA 16x16x32, 64x64 block tiles.
// ---------------------------------------------------------------------------
__global__ __launch_bounds__(256) void k_gemm(
    const float* __restrict__ u_emb,
    const float* __restrict__ i_emb,
    const unsigned short* __restrict__ McatT,  // [384][128] bf16 bits
    const float* __restrict__ cvec,            // [384]
    unsigned short* __restrict__ vp)           // [16384][384] bf16 bits
{
    __shared__ unsigned short Atile[64][136];  // +8 pad
    const int t = threadIdx.x;
    const int bm = blockIdx.x & 255;   // 256 M tiles
    const int bn = blockIdx.x >> 8;    // 6 N tiles
    const int Mbase = bm * 64;
    const int Nbase = bn * 64;

    #pragma unroll
    for (int it = 0; it < 8; ++it) {
        int idx  = it * 256 + t;       // 0..2047, each covers 4 floats
        int row  = idx >> 5;
        int colg = idx & 31;
        const float* src = (colg < 16)
            ? (u_emb + (Mbase + row) * 64 + colg * 4)
            : (i_emb + (Mbase + row) * 64 + (colg - 16) * 4);
        float4 v = *reinterpret_cast<const float4*>(src);
        ushort4 h;
        h.x = f2bu(v.x); h.y = f2bu(v.y); h.z = f2bu(v.z); h.w = f2bu(v.w);
        *reinterpret_cast<ushort4*>(&Atile[row][colg * 4]) = h;
    }
    __syncthreads();

    const int w    = t >> 6;
    const int lane = t & 63;
    const int lr   = lane & 15;
    const int lk   = (lane >> 4) * 8;

    short8 afrag[4];
    #pragma unroll
    for (int kk = 0; kk < 4; ++kk)
        afrag[kk] = *reinterpret_cast<const short8*>(&Atile[w * 16 + lr][kk * 32 + lk]);

    #pragma unroll
    for (int nt = 0; nt < 4; ++nt) {
        f32x4 acc = {0.f, 0.f, 0.f, 0.f};
        int col = Nbase + nt * 16 + lr;
        #pragma unroll
        for (int kk = 0; kk < 4; ++kk) {
            short8 bfrag = *reinterpret_cast<const short8*>(McatT + col * 128 + kk * 32 + lk);
            acc = __builtin_amdgcn_mfma_f32_16x16x32_bf16(afrag[kk], bfrag, acc, 0, 0, 0);
        }
        float cb = cvec[col];
        #pragma unroll
        for (int reg = 0; reg < 4; ++reg) {
            int grow = Mbase + w * 16 + (lane >> 4) * 4 + reg;
            vp[grow * 384 + col] = f2bu(acc[reg] + cb);
        }
    }
}

// ---------------------------------------------------------------------------
// K3: pred[t] = sum_e ao_in[t][e] * v'[b][s[t]*128 + e],  ao_in = [a|o]
//     8 lanes/triple, 8 grid-stride sweeps per thread. s is prefetched one
//     sweep ahead so the vp gather never serializes behind its own s load;
//     all other loads are affine streaming -> scheduler can pipeline deeply.
// ---------------------------------------------------------------------------
#define K3_BLOCKS 1280
#define K3_SWEEP_TRIPS (K3_BLOCKS * 32)   // 40960 triples per sweep
#define K3_SWEEPS 8                       // 327680 / 40960

__global__ __launch_bounds__(256, 5) void k_pred(
    const float* __restrict__ a_emb,
    const float* __restrict__ o_emb,
    const int* __restrict__ s,
    const unsigned short* __restrict__ vp,
    float* __restrict__ out)
{
    const int lane8 = threadIdx.x & 7;
    const int j8    = lane8 * 8;
    int trip = blockIdx.x * 32 + (threadIdx.x >> 3);

    int sv = s[trip];   // prologue: the only serialized s -> vp round trip

    #pragma unroll
    for (int it = 0; it < K3_SWEEPS; ++it) {
        const int trip_next = trip + K3_SWEEP_TRIPS;
        // prefetch next sweep's s (compile-time condition after unroll)
        int sv_next = 0;
        if (it + 1 < K3_SWEEPS) sv_next = s[trip_next];

        const float* pa = a_emb + trip * 64 + j8;
        const float* po = o_emb + trip * 64 + j8;
        float4 al = *(const float4*)(pa);
        float4 ah = *(const float4*)(pa + 4);
        float4 ol = *(const float4*)(po);
        float4 oh = *(const float4*)(po + 4);

        unsigned b = (unsigned)trip / NN;
        const unsigned short* vb = vp + (((b * 3u + (unsigned)sv) << 7));
        uint4 wa = *(const uint4*)(vb + j8);
        uint4 wb = *(const uint4*)(vb + 64 + j8);

        float r = al.x * lo16(wa.x) + al.y * hi16(wa.x)
                + al.z * lo16(wa.y) + al.w * hi16(wa.y)
                + ah.x * lo16(wa.z) + ah.y * hi16(wa.z)
                + ah.z * lo16(wa.w) + ah.w * hi16(wa.w)
                + ol.x * lo16(wb.x) + ol.y * hi16(wb.x)
                + ol.z * lo16(wb.y) + ol.w * hi16(wb.y)
                + oh.x * lo16(wb.z) + oh.y * hi16(wb.z)
                + oh.z * lo16(wb.w) + oh.w * hi16(wb.w);

        r += __shfl_xor(r, 4, 64);
        r += __shfl_xor(r, 2, 64);
        r += __shfl_xor(r, 1, 64);
        if (lane8 == 0)
            out[trip] = r;

        sv = sv_next;
        trip = trip_next;
    }
}

// ---------------------------------------------------------------------------
extern "C" void kernel_launch(void* const* d_in, const int* in_sizes, int n_in,
                              void* d_out, int out_size, void* d_ws, size_t ws_size,
                              hipStream_t stream) {
    const float* u_emb = (const float*)d_in[0];
    const float* i_emb = (const float*)d_in[1];
    const float* a_emb = (const float*)d_in[2];
    const float* o_emb = (const float*)d_in[3];
    const int*   s     = (const int*)d_in[4];
    const float* w_uir = (const float*)d_in[5];
    const float* w_aor = (const float*)d_in[6];
    const float* r_vec = (const float*)d_in[7];
    float* out = (float*)d_out;

    char* ws = (char*)d_ws;
    unsigned short* McatT = (unsigned short*)ws;              // 98304 B
    float*          cvec  = (float*)(ws + 98304);             // 1536 B
    unsigned short* vp    = (unsigned short*)(ws + 102400);   // 12.58 MB

    k_precompute<<<194, 256, 0, stream>>>(w_uir, w_aor, r_vec, McatT, cvec);
    k_gemm<<<1536, 256, 0, stream>>>(u_emb, i_emb, McatT, cvec, vp);
    k_pred<<<K3_BLOCKS, 256, 0, stream>>>(a_emb, o_emb, s, vp, out);
}

// Round 6
// 53.466 us; speedup vs baseline: 1.0431x; 1.0431x over previous
//
#include <hip/hip_runtime.h>
#include <hip/hip_bf16.h>

// Problem constants: B=16384, N=20, D=64, R=3, K=64
#define BB   16384
#define NN   20
#define NREL 3

typedef __attribute__((ext_vector_type(8))) short  short8;
typedef __attribute__((ext_vector_type(4))) float  f32x4;

__device__ __forceinline__ float lo16(unsigned int u) {
    union { unsigned int x; float f; } c; c.x = u << 16; return c.f;
}
__device__ __forceinline__ float hi16(unsigned int u) {
    union { unsigned int x; float f; } c; c.x = u & 0xFFFF0000u; return c.f;
}

// f32 -> bf16 (RNE), returned as raw ushort
__device__ __forceinline__ unsigned short f2bu(float f) {
    union { float f; unsigned int u; } x;
    x.f = f;
    unsigned int r = x.u + 0x7FFFu + ((x.u >> 16) & 1u);
    return (unsigned short)(r >> 16);
}

// ---------------------------------------------------------------------------
// K1: McatT[r*128+e][d] = sum_k w_uir[r][d][k] * w_aor[r][e][k]   (bf16 out)
//     cvec[r*128+e]     = sum_k r_vec[r][k]   * w_aor[r][e][k]    (f32 out)
// ---------------------------------------------------------------------------
__global__ __launch_bounds__(256) void k_precompute(
    const float* __restrict__ w_uir,
    const float* __restrict__ w_aor,
    const float* __restrict__ r_vec,
    unsigned short* __restrict__ McatT,   // [384][128] bf16 bits
    float* __restrict__ cvec)             // [384]
{
    int idx = blockIdx.x * 256 + threadIdx.x;
    if (idx < NREL * 128 * 128) {
        int d = idx & 127;
        int e = (idx >> 7) & 127;
        int r = idx >> 14;
        const float4* pu = reinterpret_cast<const float4*>(w_uir + (r * 128 + d) * 64);
        const float4* pa = reinterpret_cast<const float4*>(w_aor + (r * 128 + e) * 64);
        float acc = 0.f;
        #pragma unroll
        for (int k = 0; k < 16; ++k) {
            float4 a = pu[k], b = pa[k];
            acc += a.x * b.x + a.y * b.y + a.z * b.z + a.w * b.w;
        }
        McatT[(r * 128 + e) * 128 + d] = f2bu(acc);
    } else if (idx < NREL * 128 * 128 + NREL * 128) {
        int j = idx - NREL * 128 * 128;
        int r = j >> 7, e = j & 127;
        const float4* pr = reinterpret_cast<const float4*>(r_vec + r * 64);
        const float4* pa = reinterpret_cast<const float4*>(w_aor + (r * 128 + e) * 64);
        float acc = 0.f;
        #pragma unroll
        for (int k = 0; k < 16; ++k) {
            float4 a = pr[k], b = pa[k];
            acc += a.x * b.x + a.y * b.y + a.z * b.z + a.w * b.w;
        }
        cvec[j] = acc;
    }
}

// ---------------------------------------------------------------------------
// K2: v'[b][j] = sum_d ui_in[b][d] * McatT[j][d] + cvec[j]
//     GEMM M=16384 N=384 K=128, bf16 MFMA 16x16x32, 64x64 block tiles.
// ---------------------------------------------------------------------------
__global__ __launch_bounds__(256) void k_gemm(
    const float* __restrict__ u_emb,
    const float* __restrict__ i_emb,
    const unsigned short* __restrict__ McatT,  // [384][128] bf16 bits
    const float* __restrict__ cvec,            // [384]
    unsigned short* __restrict__ vp)           // [16384][384] bf16 bits
{
    __shared__ unsigned short Atile[64][136];  // +8 pad
    const int t = threadIdx.x;
    const int bm = blockIdx.x & 255;   // 256 M tiles
    const int bn = blockIdx.x >> 8;    // 6 N tiles
    const int Mbase = bm * 64;
    const int Nbase = bn * 64;

    #pragma unroll
    for (int it = 0; it < 8; ++it) {
        int idx  = it * 256 + t;       // 0..2047, each covers 4 floats
        int row  = idx >> 5;
        int colg = idx & 31;
        const float* src = (colg < 16)
            ? (u_emb + (Mbase + row) * 64 + colg * 4)
            : (i_emb + (Mbase + row) * 64 + (colg - 16) * 4);
        float4 v = *reinterpret_cast<const float4*>(src);
        ushort4 h;
        h.x = f2bu(v.x); h.y = f2bu(v.y); h.z = f2bu(v.z); h.w = f2bu(v.w);
        *reinterpret_cast<ushort4*>(&Atile[row][colg * 4]) = h;
    }
    __syncthreads();

    const int w    = t >> 6;
    const int lane = t & 63;
    const int lr   = lane & 15;
    const int lk   = (lane >> 4) * 8;

    short8 afrag[4];
    #pragma unroll
    for (int kk = 0; kk < 4; ++kk)
        afrag[kk] = *reinterpret_cast<const short8*>(&Atile[w * 16 + lr][kk * 32 + lk]);

    #pragma unroll
    for (int nt = 0; nt < 4; ++nt) {
        f32x4 acc = {0.f, 0.f, 0.f, 0.f};
        int col = Nbase + nt * 16 + lr;
        #pragma unroll
        for (int kk = 0; kk < 4; ++kk) {
            short8 bfrag = *reinterpret_cast<const short8*>(McatT + col * 128 + kk * 32 + lk);
            acc = __builtin_amdgcn_mfma_f32_16x16x32_bf16(afrag[kk], bfrag, acc, 0, 0, 0);
        }
        float cb = cvec[col];
        #pragma unroll
        for (int reg = 0; reg < 4; ++reg) {
            int grow = Mbase + w * 16 + (lane >> 4) * 4 + reg;
            vp[grow * 384 + col] = f2bu(acc[reg] + cb);
        }
    }
}

// ---------------------------------------------------------------------------
// K3: pred[t] = sum_e ao_in[t][e] * v'[b][s[t]*128 + e],  ao_in = [a|o]
//     Block owns 16 consecutive b's (320 triples). The block's vp slice
//     (16 b x 3 rel x 256B = 12KB, CONTIGUOUS in ws) is DMA'd to LDS once
//     via global_load_lds -> the per-triple relation select becomes an LDS
//     index, removing the global gather (and its latency chain) from the
//     loop. a/o are pure affine streams with a 1-deep named-register
//     rolling prefetch; s is prefetched one iter ahead.
// ---------------------------------------------------------------------------
#define K3_BLOCKS 1024          // 16384 b / 16 b per block
#define K3_BPB    16            // b's per block
#define K3_TPB    (K3_BPB * NN) // 320 triples per block
#define K3_ITERS  10            // 320 / 32 triples per iter

__global__ __launch_bounds__(256, 4) void k_pred(
    const float* __restrict__ a_emb,
    const float* __restrict__ o_emb,
    const int* __restrict__ s,
    const unsigned short* __restrict__ vp,
    float* __restrict__ out)
{
    __shared__ unsigned short vp_lds[K3_BPB * 3 * 128];  // 12288 B

    const int tid  = threadIdx.x;
    const int bid  = blockIdx.x;
    const int wv   = tid >> 6;
    const int lane = tid & 63;

    // ---- Stage vp slice: 12KB contiguous, 12 x global_load_lds dwordx4
    // (3 instrs per wave; instr k fills LDS [k*1024, k*1024+1024) )
    {
        const char* src_base = (const char*)(vp + (size_t)bid * K3_BPB * 384);
        #pragma unroll
        for (int kk = 0; kk < 3; ++kk) {
            int k = wv * 3 + kk;
            const char* src = src_base + k * 1024 + lane * 16;
            char* dst = (char*)vp_lds + k * 1024;
            __builtin_amdgcn_global_load_lds((const unsigned int*)src,
                                             (unsigned int*)dst, 16, 0, 0);
        }
    }
    asm volatile("s_waitcnt vmcnt(0)");
    __syncthreads();

    // ---- Compute: 8 lanes per triple, 10 iters, 1-deep rolling prefetch
    const int g  = tid >> 3;          // group 0..31 (triple within iter)
    const int q  = tid & 7;           // lane within group
    const int j8 = q * 8;             // element offset in 64-elem row

    int trip0 = bid * K3_TPB + g;     // iter stride is +32 triples

    // prologue: prefetch iter-0 data
    int    sv_c = s[trip0];
    const float* pa = a_emb + (size_t)trip0 * 64 + j8;
    const float* po = o_emb + (size_t)trip0 * 64 + j8;
    float4 a0c = *(const float4*)(pa);
    float4 a1c = *(const float4*)(pa + 4);
    float4 o0c = *(const float4*)(po);
    float4 o1c = *(const float4*)(po + 4);

    #pragma unroll
    for (int it = 0; it < K3_ITERS; ++it) {
        const int trip  = trip0 + it * 32;
        const int ltrip = it * 32 + g;         // local triple 0..319

        // prefetch next iteration (dead code on last iter after unroll)
        int    sv_n = 0;
        float4 a0n = {}, a1n = {}, o0n = {}, o1n = {};
        if (it + 1 < K3_ITERS) {
            const int tn = trip + 32;
            sv_n = s[tn];
            const float* pan = a_emb + (size_t)tn * 64 + j8;
            const float* pon = o_emb + (size_t)tn * 64 + j8;
            a0n = *(const float4*)(pan);
            a1n = *(const float4*)(pan + 4);
            o0n = *(const float4*)(pon);
            o1n = *(const float4*)(pon + 4);
        }

        // vp from LDS: row = bl*3 + sv  (bl = ltrip/20), 2x16B per lane
        const int bl = ltrip / NN;
        const unsigned short* vrow = vp_lds + (bl * 3 + sv_c) * 128;
        uint4 wa = *(const uint4*)(vrow + j8);
        uint4 wb = *(const uint4*)(vrow + 64 + j8);

        float r = a0c.x * lo16(wa.x) + a0c.y * hi16(wa.x)
                + a0c.z * lo16(wa.y) + a0c.w * hi16(wa.y)
                + a1c.x * lo16(wa.z) + a1c.y * hi16(wa.z)
                + a1c.z * lo16(wa.w) + a1c.w * hi16(wa.w)
                + o0c.x * lo16(wb.x) + o0c.y * hi16(wb.x)
                + o0c.z * lo16(wb.y) + o0c.w * hi16(wb.y)
                + o1c.x * lo16(wb.z) + o1c.y * hi16(wb.z)
                + o1c.z * lo16(wb.w) + o1c.w * hi16(wb.w);

        r += __shfl_xor(r, 4, 64);
        r += __shfl_xor(r, 2, 64);
        r += __shfl_xor(r, 1, 64);
        if (q == 0)
            out[trip] = r;

        // roll the pipeline
        sv_c = sv_n;
        a0c = a0n; a1c = a1n; o0c = o0n; o1c = o1n;
    }
}

// ---------------------------------------------------------------------------
extern "C" void kernel_launch(void* const* d_in, const int* in_sizes, int n_in,
                              void* d_out, int out_size, void* d_ws, size_t ws_size,
                              hipStream_t stream) {
    const float* u_emb = (const float*)d_in[0];
    const float* i_emb = (const float*)d_in[1];
    const float* a_emb = (const float*)d_in[2];
    const float* o_emb = (const float*)d_in[3];
    const int*   s     = (const int*)d_in[4];
    const float* w_uir = (const float*)d_in[5];
    const float* w_aor = (const float*)d_in[6];
    const float* r_vec = (const float*)d_in[7];
    float* out = (float*)d_out;

    char* ws = (char*)d_ws;
    unsigned short* McatT = (unsigned short*)ws;              // 98304 B
    float*          cvec  = (float*)(ws + 98304);             // 1536 B
    unsigned short* vp    = (unsigned short*)(ws + 102400);   // 12.58 MB

    k_precompute<<<194, 256, 0, stream>>>(w_uir, w_aor, r_vec, McatT, cvec);
    k_gemm<<<1536, 256, 0, stream>>>(u_emb, i_emb, McatT, cvec, vp);
    k_pred<<<K3_BLOCKS, 256, 0, stream>>>(a_emb, o_emb, s, vp, out);
}